// Round 6
// baseline (754.644 us; speedup 1.0000x reference)
//
#include <hip/hip_runtime.h>
#include <hip/hip_bf16.h>
#include <math.h>

#define T_TOK 4096
#define HID   4096
#define NHQ   32
#define NKVH  8
#define HDIM  128
#define SEQ   1024
#define NBATCH 4

typedef __attribute__((ext_vector_type(8))) short bf16x8;
typedef __attribute__((ext_vector_type(4))) float f32x4;

__device__ __forceinline__ unsigned short f2bf(float f) {
  union { float f; unsigned int u; } x; x.f = f;
  unsigned int r = x.u + 0x7FFFu + ((x.u >> 16) & 1u);
  return (unsigned short)(r >> 16);
}

// async global->LDS, 16B per lane. LDS dest must be wave-uniform base; HW adds lane*16.
#define GLOAD_LDS16(gp, lp)                                                        \
  __builtin_amdgcn_global_load_lds(                                                \
      (__attribute__((address_space(1))) void*)(unsigned long long)(const void*)(gp), \
      (__attribute__((address_space(3))) void*)(unsigned long long)(const void*)(lp), \
      16, 0, 0)

// ---------------- single fused cast fp32 -> bf16 for all 5 tensors -------------
__global__ __launch_bounds__(256) void cast_all_k(const float* __restrict__ x,
                                                  const float* __restrict__ wq,
                                                  const float* __restrict__ wk,
                                                  const float* __restrict__ wv,
                                                  const float* __restrict__ wo,
                                                  unsigned short* __restrict__ xb,
                                                  unsigned short* __restrict__ wqkv,
                                                  unsigned short* __restrict__ wob) {
  int i = blockIdx.x * 256 + threadIdx.x;  // float4 index, total 14680064
  const float* src; unsigned short* dst; int off;
  if (i < 4194304)       { src = x;  dst = xb;   off = i; }
  else if (i < 8388608)  { src = wq; dst = wqkv; off = i - 4194304; }
  else if (i < 9437184)  { src = wk; dst = wqkv + 16777216; off = i - 8388608; }
  else if (i < 10485760) { src = wv; dst = wqkv + 20971520; off = i - 9437184; }
  else                   { src = wo; dst = wob;  off = i - 10485760; }
  float4 f = ((const float4*)src)[off];
  ushort4 o;
  o.x = f2bf(f.x); o.y = f2bf(f.y); o.z = f2bf(f.z); o.w = f2bf(f.w);
  ((ushort4*)dst)[off] = o;
}

// ============== Unified GEMM: C[M,N] = A[M,K] @ B[N,K]^T, 256x256 tile ========
// BK=32, 8 waves (2M x 4N), per-wave 128x64 (FLOP/LDS-byte = 42.7).
// N-frag interleave for RoPE: wave wn -> head hh=wn>>1, base bb=(wn&1)*32;
// frag nf col = hh*128 + bb + (nf&1)*16 + (nf>>1)*64 (+m16). Pair (d,d+64)
// in-lane at frags e / e+2.
// LDS: ring-4 x (A 16KB + B 16KB) = 128 KB. Packed 2-rows-per-128B layout,
// slot = (q + 4*(row&1)) ^ (prow&7)  (R5 gemm_o layout, correctness-proven).
// Pipeline (ring-4, stage depth 3, per tile t):
//   stage(t+3) -> vmcnt(4) [retires batch(t+2); batch(t+1) retired LAST tile
//   so its all-waves visibility was confirmed at the LAST barrier] ->
//   MFMA(t) x32 with reads(t+1) scheduler-interleaved after last frag uses ->
//   raw s_barrier. No drains in steady state; prologue vmcnt(4) pays HBM once.
template<bool FUSED>
__global__ __launch_bounds__(512, 1) void gemm256(const unsigned short* __restrict__ A,
                                                  const unsigned short* __restrict__ B,
                                                  float* __restrict__ C,
                                                  const int* __restrict__ pos,
                                                  unsigned short* __restrict__ qr,
                                                  unsigned short* __restrict__ kr,
                                                  unsigned short* __restrict__ vbuf,
                                                  int N) {
  const int K = 4096, nt = 128;
  __shared__ unsigned short AS[4][8192];   // 64 KB: [128 prow][64 sh] per slot
  __shared__ unsigned short BS[4][8192];   // 64 KB
  const int tid  = threadIdx.x;
  const int lane = tid & 63;
  const int wave = tid >> 6;
  const int m16  = lane & 15;
  const int quad = lane >> 4;
  const int wm   = wave >> 2;        // 0..1: rows wm*128..+127
  const int wn   = wave & 3;
  const int hh   = wn >> 1;          // head-half within 256-col tile
  const int bb   = (wn & 1) * 32;

  // XCD-aware swizzle (nwg = 384 or 256, both %8==0)
  const int gx = gridDim.x;
  const int nwg = gx * gridDim.y;
  const int orig = blockIdx.y * gx + blockIdx.x;
  const int swz = (orig & 7) * (nwg >> 3) + (orig >> 3);
  const long rowBase = (long)(swz / gx) * 256;
  const long colBase = (long)(swz % gx) * 256;

  // frag read offsets (shorts): prow&7 == m16>>1 for all frags
  const int slot8 = ((quad + 4 * (m16 & 1)) ^ (m16 >> 1)) * 8;
  const int aob = (wm * 64 + (m16 >> 1)) * 64 + slot8;                      // + mf*512
  const int bob = (hh * 64 + (wn & 1) * 16 + (m16 >> 1)) * 64 + slot8;      // + (nf&1)*512 + (nf>>1)*2048

  // staging source (inverse of packed swizzle)
  const long Kl = K;
  const int z = (tid & 7) ^ ((tid >> 3) & 7);
  const long srow = 2 * (tid >> 3) + (z >> 2);
  const int sk = (z & 3) * 8;
  const unsigned short* sA = A + (rowBase + srow) * Kl + sk;
  const unsigned short* sB = B + (colBase + srow) * Kl + sk;
  const int dofs = wave * 512;

#define STG_A(sl_, ko_) { GLOAD_LDS16(sA + (ko_),            &AS[sl_][dofs]);         \
                          GLOAD_LDS16(sA + (ko_) + 128 * Kl, &AS[sl_][4096 + dofs]); }
#define STG_B(sl_, ko_) { GLOAD_LDS16(sB + (ko_),            &BS[sl_][dofs]);         \
                          GLOAD_LDS16(sB + (ko_) + 128 * Kl, &BS[sl_][4096 + dofs]); }

#define RD_TILE(sl_) {                                                               \
    _Pragma("unroll")                                                                \
    for (int nf = 0; nf < 4; ++nf)                                                   \
      bfr[nf] = *(const bf16x8*)(&BS[sl_][bob + (nf & 1) * 512 + (nf >> 1) * 2048]); \
    _Pragma("unroll")                                                                \
    for (int mf = 0; mf < 8; ++mf)                                                   \
      af[mf] = *(const bf16x8*)(&AS[sl_][aob + mf * 512]); }

  f32x4 acc[8][4] = {};   // [mf][nf]
  bf16x8 af[8], bfr[4];

  // prologue: stage tiles 0,1,2 (batches of 4 loads, FIFO); confirm 0 AND 1.
  STG_A(0, 0);  STG_B(0, 0);
  STG_A(1, 32); STG_B(1, 32);
  STG_A(2, 64); STG_B(2, 64);
  asm volatile("s_waitcnt vmcnt(4)" ::: "memory");   // batches 0,1 landed (one-time stall)
  __builtin_amdgcn_s_barrier();
  RD_TILE(0);

  for (int g = 0; g < 32; ++g) {
#pragma unroll
    for (int u = 0; u < 4; ++u) {
      const int t = g * 4 + u;
      // stage batch for t+3 into slot (u+3)&3 (never aliases t, t+1, t+2)
      if (t + 3 < nt) { STG_A((u + 3) & 3, (t + 3) * 32); STG_B((u + 3) & 3, (t + 3) * 32); }
      // retire batch(t+2) (its reads happen next tile, after the barrier below)
      if (t + 3 < nt) asm volatile("s_waitcnt vmcnt(4)" ::: "memory");
      else            asm volatile("s_waitcnt vmcnt(0)" ::: "memory");
      __builtin_amdgcn_s_setprio(1);
#pragma unroll
      for (int mf = 0; mf < 8; ++mf)
#pragma unroll
        for (int nf = 0; nf < 4; ++nf)
          acc[mf][nf] = __builtin_amdgcn_mfma_f32_16x16x32_bf16(af[mf], bfr[nf], acc[mf][nf], 0, 0, 0);
      __builtin_amdgcn_s_setprio(0);
      // reads for t+1 (slot (u+1)&3): staged during t-2, retired at tile t-1's
      // vmcnt, visibility confirmed at tile t-1's barrier -> safe pre-barrier.
      // WAR on af/bfr lets the scheduler interleave these under the MFMAs.
      if (t + 1 < nt) RD_TILE((u + 1) & 3);
      __builtin_amdgcn_s_barrier();
    }
  }

  if (!FUSED) {
#pragma unroll
    for (int mf = 0; mf < 8; ++mf)
#pragma unroll
      for (int nf = 0; nf < 4; ++nf) {
        long c = colBase + hh * 128 + bb + (nf & 1) * 16 + (nf >> 1) * 64 + m16;
#pragma unroll
        for (int reg = 0; reg < 4; ++reg) {
          long row = rowBase + wm * 128 + mf * 16 + quad * 4 + reg;
          C[row * N + c] = acc[mf][nf][reg];
        }
      }
    return;
  }

  // ---- fused epilogue: RoPE (q/k) or plain (v), bf16 scatter ----
  const int n0 = (int)colBase;   // 256-aligned; whole block in one of q/k/v
  unsigned short* dst;
  int rstride, colofs0;
  bool dorope;
  if (n0 < 4096)       { dst = qr;   rstride = NHQ * HDIM;  colofs0 = n0;        dorope = true; }
  else if (n0 < 5120)  { dst = kr;   rstride = NKVH * HDIM; colofs0 = n0 - 4096; dorope = true; }
  else                 { dst = vbuf; rstride = NKVH * HDIM; colofs0 = n0 - 5120; dorope = false; }
  const int colofs = colofs0 + hh * 128;
  const float c0 = -13.287712379549449f / 64.0f;  // -log2(10000)/64
  float fA[2], fB[2];
#pragma unroll
  for (int e = 0; e < 2; ++e) {
    int d = bb + e * 16 + m16;
    fA[e] = exp2f(c0 * (float)(d >> 1));
    fB[e] = exp2f(c0 * (float)((d >> 1) + 32));
  }
#pragma unroll
  for (int mf = 0; mf < 8; ++mf) {
#pragma unroll
    for (int reg = 0; reg < 4; ++reg) {
      int grow = (int)rowBase + wm * 128 + mf * 16 + quad * 4 + reg;
      unsigned short* drow = dst + (long)grow * rstride + colofs;
      if (dorope) {
        int p = pos[grow];
        p = p < 0 ? 0 : (p > SEQ - 1 ? SEQ - 1 : p);
        float pf = (float)p;
#pragma unroll
        for (int e = 0; e < 2; ++e) {
          int d = bb + e * 16 + m16;
          float lo = acc[mf][e][reg], hi = acc[mf][e + 2][reg];
          float s1, cc1, s2, cc2;
          __sincosf(pf * fA[e], &s1, &cc1);
          __sincosf(pf * fB[e], &s2, &cc2);
          drow[d]      = f2bf(lo * cc1 - hi * s1);
          drow[d + 64] = f2bf(hi * cc2 + lo * s2);
        }
      } else {
#pragma unroll
        for (int e = 0; e < 2; ++e) {
          int d = bb + e * 16 + m16;
          drow[d]      = f2bf(acc[mf][e][reg]);
          drow[d + 64] = f2bf(acc[mf][e + 2][reg]);
        }
      }
    }
  }
}

// ---------------- Flash attention (causal, GQA), bf16 MFMA ----------------
// 64 KB LDS (Ks dbuf + single Vt + Ps) -> 2 blocks/CU, 2 waves/SIMD, grid
// fits in ONE dispatch round. V reg-staged (T14); scatter behind 2nd barrier.
#define ATT_SCALE_L2 0.12754227022f  // (1/sqrt(128)) * log2(e)
__global__ __launch_bounds__(256) void attn_k(const unsigned short* __restrict__ Qp,
                                              const unsigned short* __restrict__ Kp,
                                              const unsigned short* __restrict__ Vp,
                                              unsigned short* __restrict__ Op) {
  const int pr = blockIdx.x, h = blockIdx.y, b = blockIdx.z;
  const int kvh = h >> 2;
  const int tid = threadIdx.x, wave = tid >> 6, lane = tid & 63;
  const int m16 = lane & 15, quad = lane >> 4;

  __shared__ unsigned short Ks[2][64][128];   // 32 KB dbuf [key][d], xor swizzle
  __shared__ unsigned short Vt[128][64];      // 16 KB single [d][key], rotation
  __shared__ unsigned short Ps[4][32][64];    // 16 KB per-wave P

  const unsigned short* Kh = Kp + (long)(b * SEQ) * (NKVH * HDIM) + kvh * HDIM;
  const unsigned short* Vh = Vp + (long)(b * SEQ) * (NKVH * HDIM) + kvh * HDIM;

#define STAGE_K(ktv, bufp) {                                               \
    _Pragma("unroll")                                                      \
    for (int it_ = 0; it_ < 4; ++it_) {                                    \
      int c_ = it_ * 256 + tid;                                            \
      int row_ = c_ >> 4, psg_ = c_ & 15;                                  \
      int sg_ = (psg_ & 8) | ((psg_ & 7) ^ (row_ & 7));                    \
      GLOAD_LDS16(Kh + ((long)(ktv) * 64 + row_) * (NKVH * HDIM) + sg_ * 8,\
                  ((unsigned short*)(bufp)) + (it_ * 256 + wave * 64) * 8);\
    } }

#define LOAD_V(ktv, dvv) {                                                 \
    _Pragma("unroll")                                                      \
    for (int it_ = 0; it_ < 4; ++it_)                                      \
      dvv[it_] = *(const uint4*)(Vh + ((long)(ktv) * 64 + lane) * (NKVH * HDIM) + (it_ * 4 + wave) * 8); }

#define SCATTER_V(dvv) {                                                   \
    _Pragma("unroll")                                                      \
    for (int it_ = 0; it_ < 4; ++it_) {                                    \
      const unsigned short* pv_ = (const unsigned short*)&dvv[it_];        \
      int seg_ = it_ * 4 + wave;                                           \
      _Pragma("unroll")                                                    \
      for (int e_ = 0; e_ < 8; ++e_) {                                     \
        int d_ = seg_ * 8 + e_;                                            \
        Vt[d_][((((lane >> 3) + d_) & 7) * 8) + (lane & 7)] = pv_[e_];     \
      } } }

  for (int pass = 0; pass < 2; ++pass) {
    const int qt = pass ? pr : (7 - pr);
    const int qbase = qt * 128;
    const int wq_lo = qbase + wave * 32;

    bf16x8 qa[2][4];
#pragma unroll
    for (int i = 0; i < 2; ++i) {
      const unsigned short* qrow =
          Qp + (long)(b * SEQ + wq_lo + i * 16 + m16) * (NHQ * HDIM) + h * HDIM;
#pragma unroll
      for (int kk = 0; kk < 4; ++kk)
        qa[i][kk] = *(const bf16x8*)(qrow + kk * 32 + quad * 8);
    }

    f32x4 o[2][8] = {};
    float mrow[2][4], lrow[2][4];
#pragma unroll
    for (int i = 0; i < 2; ++i)
#pragma unroll
      for (int r = 0; r < 4; ++r) { mrow[i][r] = -1e30f; lrow[i][r] = 0.f; }

    const int nkt = qt * 2 + 2;

    {  // prologue: K0 -> Ks[0], V0 -> Vt
      STAGE_K(0, Ks[0]);
      uint4 dv0[4];
      LOAD_V(0, dv0);
      asm volatile("s_waitcnt vmcnt(0)" ::: "memory");
      SCATTER_V(dv0);
    }
    __syncthreads();

    for (int kt = 0; kt < nkt; ++kt) {
      const int cb = kt & 1;
      const bool active = (kt * 64) <= (wq_lo + 31);
      const bool more = (kt + 1) < nkt;

      f32x4 s4[2][4] = {};
      if (active) {
        __builtin_amdgcn_s_setprio(1);
#pragma unroll
        for (int kk = 0; kk < 4; ++kk) {
          bf16x8 kbf[4];
#pragma unroll
          for (int j = 0; j < 4; ++j) {
            int row = j * 16 + m16;
            int cl = kk * 4 + quad;
            int ps = (cl & 8) | ((cl & 7) ^ (row & 7));
            kbf[j] = *(const bf16x8*)(&Ks[cb][row][ps * 8]);
          }
#pragma unroll
          for (int i = 0; i < 2; ++i)
#pragma unroll
            for (int j = 0; j < 4; ++j)
              s4[i][j] = __builtin_amdgcn_mfma_f32_16x16x32_bf16(qa[i][kk], kbf[j], s4[i][j], 0, 0, 0);
        }
        __builtin_amdgcn_s_setprio(0);
      }

      // T14: issue next tile's K staging + V reg loads; they hide under softmax+PV
      uint4 dv[4];
      if (more) {
        STAGE_K(kt + 1, Ks[cb ^ 1]);
        LOAD_V(kt + 1, dv);
      }
      asm volatile("" ::: "memory");

      if (active) {
        const bool full = (kt * 64 + 63) <= wq_lo;
#pragma unroll
        for (int i = 0; i < 2; ++i) {
#pragma unroll
          for (int r = 0; r < 4; ++r) {
            const int qrow = i * 16 + quad * 4 + r;
            const int qi = qbase + wave * 32 + qrow;
            float v[4];
#pragma unroll
            for (int j = 0; j < 4; ++j) {
              v[j] = s4[i][j][r] * ATT_SCALE_L2;
              if (!full && (kt * 64 + j * 16 + m16 > qi)) v[j] = -1e30f;
            }
            float mx = fmaxf(fmaxf(v[0], v[1]), fmaxf(v[2], v[3]));
            mx = fmaxf(mx, __shfl_xor(mx, 1));
            mx = fmaxf(mx, __shfl_xor(mx, 2));
            mx = fmaxf(mx, __shfl_xor(mx, 4));
            mx = fmaxf(mx, __shfl_xor(mx, 8));
            float mold = mrow[i][r];
            float mnew = fmaxf(mold, mx);
            float alpha = exp2f(mold - mnew);
            float rs = 0.f;
#pragma unroll
            for (int j = 0; j < 4; ++j) {
              float pj = exp2f(v[j] - mnew);
              rs += pj;
              int col = j * 16 + m16;
              Ps[wave][qrow][((((col >> 3) + qrow) & 7) * 8) + (col & 7)] = f2bf(pj);
            }
            rs += __shfl_xor(rs, 1); rs += __shfl_xor(rs, 2);
            rs += __shfl_xor(rs, 4); rs += __shfl_xor(rs, 8);
            lrow[i][r] = lrow[i][r] * alpha + rs;
            mrow[i][r] = mnew;
#pragma unroll
            for (int n = 0; n < 8; ++n) o[i][n][r] *= alpha;
          }
        }
        __builtin_amdgcn_s_setprio(1);
#pragma unroll
        for (int kk = 0; kk < 2; ++kk) {
          bf16x8 pa[2], vb[8];
#pragma unroll
          for (int i = 0; i < 2; ++i) {
            int row = i * 16 + m16;
            pa[i] = *(const bf16x8*)(&Ps[wave][row][(((kk * 4 + quad) + row) & 7) * 8]);
          }
#pragma unroll
          for (int n = 0; n < 8; ++n) {
            int row = n * 16 + m16;
            vb[n] = *(const bf16x8*)(&Vt[row][(((kk * 4 + quad) + row) & 7) * 8]);
          }
#pragma unroll
          for (int i = 0; i < 2; ++i)
#pragma unroll
            for (int n = 0; n < 8; ++n)
              o[i][n] = __builtin_amdgcn_mfma_f32_16x16x32_bf16(pa[i], vb[n], o[i][n], 0, 0, 0);
        }
        __builtin_amdgcn_s_setprio(0);
      }

      __syncthreads();                 // all PV reads of Vt done (drains loads too)
      if (more) SCATTER_V(dv);         // dv waited automatically before use
      __syncthreads();                 // scatter visible before next PV
    }

#pragma unroll
    for (int i = 0; i < 2; ++i) {
#pragma unroll
      for (int r = 0; r < 4; ++r) {
        float inv = 1.0f / lrow[i][r];
        unsigned short* orow =
            Op + (long)(b * SEQ + wq_lo + i * 16 + quad * 4 + r) * (NHQ * HDIM) + h * HDIM;
#pragma unroll
        for (int n = 0; n < 8; ++n)
          orow[n * 16 + m16] = f2bf(o[i][n][r] * inv);
      }
    }
  }
}

// ---------------- launch ----------------
extern "C" void kernel_launch(void* const* d_in, const int* in_sizes, int n_in,
                              void* d_out, int out_size, void* d_ws, size_t ws_size,
                              hipStream_t stream) {
  (void)in_sizes; (void)n_in; (void)out_size; (void)ws_size;
  const float* x  = (const float*)d_in[0];
  const int* pos  = (const int*)d_in[1];
  const float* wq = (const float*)d_in[3];
  const float* wk = (const float*)d_in[4];
  const float* wv = (const float*)d_in[5];
  const float* wo = (const float*)d_in[6];
  float* out = (float*)d_out;

  char* ws = (char*)d_ws;
  unsigned short* xb    = (unsigned short*)(ws);                   // 32MB bf16 x
  unsigned short* wqkv  = (unsigned short*)(ws + (32ll << 20));    // 48MB bf16 [wq;wk;wv]
  unsigned short* wob   = (unsigned short*)(ws + (80ll << 20));    // 32MB bf16 wo
  unsigned short* qr    = (unsigned short*)(ws + (112ll << 20));   // 32MB q roped bf16
  unsigned short* kr    = (unsigned short*)(ws + (144ll << 20));   // 8MB  k roped bf16
  unsigned short* vb_   = (unsigned short*)(ws + (152ll << 20));   // 8MB  v bf16
  unsigned short* ao    = (unsigned short*)(ws + (160ll << 20));   // 32MB attn out bf16

  cast_all_k<<<57344, 256, 0, stream>>>(x, wq, wk, wv, wo, xb, wqkv, wob);
  gemm256<true><<<dim3(24, 16), 512, 0, stream>>>(xb, wqkv, nullptr, pos, qr, kr, vb_, 6144);
  attn_k<<<dim3(4, 32, 4), 256, 0, stream>>>(qr, kr, vb_, ao);
  gemm256<false><<<dim3(16, 16), 512, 0, stream>>>(ao, wob, out, nullptr, nullptr, nullptr, nullptr, 4096);
}

// Round 7
// 744.410 us; speedup vs baseline: 1.0137x; 1.0137x over previous
//
#include <hip/hip_runtime.h>
#include <hip/hip_bf16.h>
#include <math.h>

#define T_TOK 4096
#define HID   4096
#define NHQ   32
#define NKVH  8
#define HDIM  128
#define SEQ   1024
#define NBATCH 4

typedef __attribute__((ext_vector_type(8))) short bf16x8;
typedef __attribute__((ext_vector_type(4))) float f32x4;

__device__ __forceinline__ unsigned short f2bf(float f) {
  union { float f; unsigned int u; } x; x.f = f;
  unsigned int r = x.u + 0x7FFFu + ((x.u >> 16) & 1u);
  return (unsigned short)(r >> 16);
}

// async global->LDS, 16B per lane. LDS dest must be wave-uniform base; HW adds lane*16.
#define GLOAD_LDS16(gp, lp)                                                        \
  __builtin_amdgcn_global_load_lds(                                                \
      (__attribute__((address_space(1))) void*)(unsigned long long)(const void*)(gp), \
      (__attribute__((address_space(3))) void*)(unsigned long long)(const void*)(lp), \
      16, 0, 0)

// ---------------- single fused cast fp32 -> bf16 for all 5 tensors -------------
__global__ __launch_bounds__(256) void cast_all_k(const float* __restrict__ x,
                                                  const float* __restrict__ wq,
                                                  const float* __restrict__ wk,
                                                  const float* __restrict__ wv,
                                                  const float* __restrict__ wo,
                                                  unsigned short* __restrict__ xb,
                                                  unsigned short* __restrict__ wqkv,
                                                  unsigned short* __restrict__ wob) {
  int i = blockIdx.x * 256 + threadIdx.x;  // float4 index, total 14680064
  const float* src; unsigned short* dst; int off;
  if (i < 4194304)       { src = x;  dst = xb;   off = i; }
  else if (i < 8388608)  { src = wq; dst = wqkv; off = i - 4194304; }
  else if (i < 9437184)  { src = wk; dst = wqkv + 16777216; off = i - 8388608; }
  else if (i < 10485760) { src = wv; dst = wqkv + 20971520; off = i - 9437184; }
  else                   { src = wo; dst = wob;  off = i - 10485760; }
  float4 f = ((const float4*)src)[off];
  ushort4 o;
  o.x = f2bf(f.x); o.y = f2bf(f.y); o.z = f2bf(f.z); o.w = f2bf(f.w);
  ((ushort4*)dst)[off] = o;
}

// ============ 8-phase quadrant GEMM: C[M,N] = A[M,K] @ B[N,K]^T ================
// 256x256 tile, BK=64 K-steps, 8 waves. Per PHASE all 8 waves compute ONE
// 128x128 C-quadrant (qa,qb) using only A-half qa + B-half qb of the current
// K-step: wave (wm2=wave>>2, wn2=wave&3) does rows wm2*64+mf*16, cols
// wn2*16 + nf*64 (nf pairing -> RoPE (d,d+64) in-lane), 4mf x 2nf x 2ks = 16 MFMA.
// Quadrant order (00),(01),(11),(10); B-frags register-reused (b0: ph0&ph3,
// b1: ph1&ph2) so each LDS half-region is ds_read in EXACTLY ONE phase.
// LDS: A[2dbuf][2half][128][64] + B same = 128 KB. Swizzle: slot = chunk ^
// (row&7) (R3-verified 0 conflicts); staging via pre-swizzled global source.
// Staging: 1 half-tile (2 gloads) per phase: ph0: Bh0(n+1)->d^1; ph1:
// Ah0(n+2)->d; ph2: Bh1(n+2)->d; ph3: Ah1(n+2)->d. Each target region's last
// read was >=1 full phase earlier (race-free with latency margin on top).
// vmcnt(6) ONLY at ph3: retires all of K-step n+1 (4 HT), keeps the 3 newest
// HTs (of n+2) in flight across the barrier. Never drains in steady state.
template<bool FUSED>
__global__ __launch_bounds__(512, 1) void gemm8p(const unsigned short* __restrict__ A,
                                                 const unsigned short* __restrict__ B,
                                                 float* __restrict__ C,
                                                 const int* __restrict__ pos,
                                                 unsigned short* __restrict__ qr,
                                                 unsigned short* __restrict__ kr,
                                                 unsigned short* __restrict__ vbuf,
                                                 int N) {
  const int K = 4096, nt = 64;                  // 64 K-steps of 64
  __shared__ unsigned short AS[2][2][128][64];  // 64 KB [dbuf][half][row][col]
  __shared__ unsigned short BS[2][2][128][64];  // 64 KB
  const int tid  = threadIdx.x;
  const int lane = tid & 63;
  const int wave = tid >> 6;
  const int m16  = lane & 15;
  const int quad = lane >> 4;
  const int wm2  = wave >> 2;   // 0..1
  const int wn2  = wave & 3;    // 0..3

  // XCD-aware swizzle (nwg = 384 or 256, both %8==0)
  const int gx = gridDim.x;
  const int nwg = gx * gridDim.y;
  const int orig = blockIdx.y * gx + blockIdx.x;
  const int swz = (orig & 7) * (nwg >> 3) + (orig >> 3);
  const long rowBase = (long)(swz / gx) * 256;
  const long colBase = (long)(swz % gx) * 256;

  // loop-invariant LDS frag read offsets (shorts), within a [128][64] half
  int aof[2], bof[2];
#pragma unroll
  for (int ks = 0; ks < 2; ++ks) {
    int sx = ((ks * 4 + quad) ^ (m16 & 7)) * 8;
    aof[ks] = (wm2 * 64 + m16) * 64 + sx;   // + mf*1024
    bof[ks] = (wn2 * 16 + m16) * 64 + sx;   // + nf*4096
  }

  // staging source (inverse swizzle; R3-verified)
  const long Kl = K;
  const int sck = ((tid & 7) ^ ((tid >> 3) & 7)) * 8;
  const unsigned short* gA = A + (rowBase + (tid >> 3)) * Kl + sck;
  const unsigned short* gB = B + (colBase + (tid >> 3)) * Kl + sck;
  const int dofs = wave * 512;  // shorts; per-call dest covers 64 rows (8KB)

#define STG(XS_, gX_, db_, hf_, ko_) {                                                      \
    GLOAD_LDS16(gX_ + (long)((hf_) * 128) * Kl + (ko_),      ((unsigned short*)&XS_[db_][hf_][0][0]) + dofs);  \
    GLOAD_LDS16(gX_ + (long)((hf_) * 128 + 64) * Kl + (ko_), ((unsigned short*)&XS_[db_][hf_][64][0]) + dofs); }

#define RD_A(d_, qa_) {                                                   \
    const unsigned short* Ah_ = &AS[d_][qa_][0][0];                       \
    _Pragma("unroll") for (int mf = 0; mf < 4; ++mf)                      \
      _Pragma("unroll") for (int ks = 0; ks < 2; ++ks)                    \
        af[mf][ks] = *(const bf16x8*)(Ah_ + aof[ks] + mf * 1024); }

#define RD_B(d_, qb_, dst_) {                                             \
    const unsigned short* Bh_ = &BS[d_][qb_][0][0];                       \
    _Pragma("unroll") for (int nf = 0; nf < 2; ++nf)                      \
      _Pragma("unroll") for (int ks = 0; ks < 2; ++ks)                    \
        dst_[nf][ks] = *(const bf16x8*)(Bh_ + bof[ks] + nf * 4096); }

#define MFMA16(qa_, qb_, b_) {                                            \
    _Pragma("unroll") for (int mf = 0; mf < 4; ++mf)                      \
      _Pragma("unroll") for (int nf = 0; nf < 2; ++nf)                    \
        _Pragma("unroll") for (int ks = 0; ks < 2; ++ks)                  \
          acc[qa_][qb_][mf][nf] = __builtin_amdgcn_mfma_f32_16x16x32_bf16(\
              af[mf][ks], b_[nf][ks], acc[qa_][qb_][mf][nf], 0, 0, 0); }

  f32x4 acc[2][2][4][2] = {};   // [qa][qb][mf][nf]
  bf16x8 af[4][2], b0[2][2], b1[2][2];

  // prologue: FIFO-stage K-step0 fully + 3 half-tiles of K-step1 (14 loads)
  STG(AS, gA, 0, 0, 0);   STG(BS, gB, 0, 1, 0);
  STG(AS, gA, 0, 1, 0);   STG(BS, gB, 0, 0, 0);
  STG(AS, gA, 1, 0, 64);  STG(BS, gB, 1, 1, 64);
  STG(AS, gA, 1, 1, 64);
  asm volatile("s_waitcnt vmcnt(6)" ::: "memory");   // K-step0 landed; 3 HT in flight
  __builtin_amdgcn_s_barrier();

#define KSTEP(n_, d_) {                                                               \
    /* ph0: quadrant (0,0) — 12 ds_read, stage Bh0(n+1) */                            \
    RD_A(d_, 0); RD_B(d_, 0, b0);                                                     \
    if ((n_) + 1 < nt) STG(BS, gB, (d_) ^ 1, 0, ((n_) + 1) * 64);                     \
    asm volatile("s_waitcnt lgkmcnt(8)" ::: "memory");                                \
    __builtin_amdgcn_s_barrier();                                                     \
    asm volatile("s_waitcnt lgkmcnt(0)" ::: "memory");                                \
    __builtin_amdgcn_s_setprio(1); MFMA16(0, 0, b0); __builtin_amdgcn_s_setprio(0);   \
    __builtin_amdgcn_s_barrier();                                                     \
    /* ph1: quadrant (0,1) — 4 ds_read, stage Ah0(n+2) */                             \
    RD_B(d_, 1, b1);                                                                  \
    if ((n_) + 2 < nt) STG(AS, gA, d_, 0, ((n_) + 2) * 64);                           \
    __builtin_amdgcn_s_barrier();                                                     \
    asm volatile("s_waitcnt lgkmcnt(0)" ::: "memory");                                \
    __builtin_amdgcn_s_setprio(1); MFMA16(0, 1, b1); __builtin_amdgcn_s_setprio(0);   \
    __builtin_amdgcn_s_barrier();                                                     \
    /* ph2: quadrant (1,1) — 8 ds_read, stage Bh1(n+2) */                             \
    RD_A(d_, 1);                                                                      \
    if ((n_) + 2 < nt) STG(BS, gB, d_, 1, ((n_) + 2) * 64);                           \
    __builtin_amdgcn_s_barrier();                                                     \
    asm volatile("s_waitcnt lgkmcnt(0)" ::: "memory");                                \
    __builtin_amdgcn_s_setprio(1); MFMA16(1, 1, b1); __builtin_amdgcn_s_setprio(0);   \
    __builtin_amdgcn_s_barrier();                                                     \
    /* ph3: quadrant (1,0) — 0 ds_read, stage Ah1(n+2), counted vmcnt */              \
    if ((n_) + 2 < nt) STG(AS, gA, d_, 1, ((n_) + 2) * 64);                           \
    __builtin_amdgcn_s_barrier();                                                     \
    __builtin_amdgcn_s_setprio(1); MFMA16(1, 0, b0); __builtin_amdgcn_s_setprio(0);   \
    if ((n_) + 2 < nt) asm volatile("s_waitcnt vmcnt(6)" ::: "memory");               \
    else               asm volatile("s_waitcnt vmcnt(0)" ::: "memory");               \
    __builtin_amdgcn_s_barrier(); }

  for (int it = 0; it < 32; ++it) {
    KSTEP(2 * it, 0);
    KSTEP(2 * it + 1, 1);
  }

  if (!FUSED) {
#pragma unroll
    for (int qa = 0; qa < 2; ++qa)
#pragma unroll
      for (int qb = 0; qb < 2; ++qb)
#pragma unroll
        for (int mf = 0; mf < 4; ++mf)
#pragma unroll
          for (int nf = 0; nf < 2; ++nf) {
            long c = colBase + qb * 128 + wn2 * 16 + nf * 64 + m16;
#pragma unroll
            for (int reg = 0; reg < 4; ++reg) {
              long row = rowBase + qa * 128 + wm2 * 64 + mf * 16 + quad * 4 + reg;
              C[row * N + c] = acc[qa][qb][mf][nf][reg];
            }
          }
    return;
  }

  // ---- fused epilogue: RoPE (q/k) or plain (v), bf16 scatter ----
  // colBase is 256-aligned and q/k/v boundaries (4096, 5120) are too -> whole
  // block (both qb windows) lands in one destination tensor.
  const int n0 = (int)colBase;
  unsigned short* dst; long rstride; int colofs; bool dorope;
  if (n0 < 4096)       { dst = qr;   rstride = NHQ * HDIM;  colofs = n0;        dorope = true; }
  else if (n0 < 5120)  { dst = kr;   rstride = NKVH * HDIM; colofs = n0 - 4096; dorope = true; }
  else                 { dst = vbuf; rstride = NKVH * HDIM; colofs = n0 - 5120; dorope = false; }
  const float c0v = -13.287712379549449f / 64.0f;  // -log2(10000)/64
  const int dD = wn2 * 16 + m16;                   // 0..63, fixed per lane
  const float f1 = exp2f(c0v * (float)(dD >> 1));
  const float f2 = exp2f(c0v * (float)((dD >> 1) + 32));
#pragma unroll
  for (int qa = 0; qa < 2; ++qa)
#pragma unroll
    for (int mf = 0; mf < 4; ++mf)
#pragma unroll
      for (int reg = 0; reg < 4; ++reg) {
        int grow = (int)rowBase + qa * 128 + wm2 * 64 + mf * 16 + quad * 4 + reg;
        unsigned short* drow = dst + (long)grow * rstride + colofs;
        if (dorope) {
          int p = pos[grow];
          p = p < 0 ? 0 : (p > SEQ - 1 ? SEQ - 1 : p);
          float pf = (float)p;
          float s1, c1, s2, c2;
          __sincosf(pf * f1, &s1, &c1);
          __sincosf(pf * f2, &s2, &c2);
#pragma unroll
          for (int qb = 0; qb < 2; ++qb) {
            float lo = acc[qa][qb][mf][0][reg], hi = acc[qa][qb][mf][1][reg];
            drow[qb * 128 + dD]      = f2bf(lo * c1 - hi * s1);
            drow[qb * 128 + dD + 64] = f2bf(hi * c2 + lo * s2);
          }
        } else {
#pragma unroll
          for (int qb = 0; qb < 2; ++qb) {
            drow[qb * 128 + dD]      = f2bf(acc[qa][qb][mf][0][reg]);
            drow[qb * 128 + dD + 64] = f2bf(acc[qa][qb][mf][1][reg]);
          }
        }
      }
}

// ---------------- Flash attention (causal, GQA), bf16 MFMA ----------------
// 64 KB LDS (Ks dbuf + single Vt + Ps) -> 2 blocks/CU, grid fits one round.
#define ATT_SCALE_L2 0.12754227022f  // (1/sqrt(128)) * log2(e)
__global__ __launch_bounds__(256) void attn_k(const unsigned short* __restrict__ Qp,
                                              const unsigned short* __restrict__ Kp,
                                              const unsigned short* __restrict__ Vp,
                                              unsigned short* __restrict__ Op) {
  const int pr = blockIdx.x, h = blockIdx.y, b = blockIdx.z;
  const int kvh = h >> 2;
  const int tid = threadIdx.x, wave = tid >> 6, lane = tid & 63;
  const int m16 = lane & 15, quad = lane >> 4;

  __shared__ unsigned short Ks[2][64][128];   // 32 KB dbuf [key][d], xor swizzle
  __shared__ unsigned short Vt[128][64];      // 16 KB single [d][key], rotation
  __shared__ unsigned short Ps[4][32][64];    // 16 KB per-wave P

  const unsigned short* Kh = Kp + (long)(b * SEQ) * (NKVH * HDIM) + kvh * HDIM;
  const unsigned short* Vh = Vp + (long)(b * SEQ) * (NKVH * HDIM) + kvh * HDIM;

#define STAGE_K(ktv, bufp) {                                               \
    _Pragma("unroll")                                                      \
    for (int it_ = 0; it_ < 4; ++it_) {                                    \
      int c_ = it_ * 256 + tid;                                            \
      int row_ = c_ >> 4, psg_ = c_ & 15;                                  \
      int sg_ = (psg_ & 8) | ((psg_ & 7) ^ (row_ & 7));                    \
      GLOAD_LDS16(Kh + ((long)(ktv) * 64 + row_) * (NKVH * HDIM) + sg_ * 8,\
                  ((unsigned short*)(bufp)) + (it_ * 256 + wave * 64) * 8);\
    } }

#define LOAD_V(ktv, dvv) {                                                 \
    _Pragma("unroll")                                                      \
    for (int it_ = 0; it_ < 4; ++it_)                                      \
      dvv[it_] = *(const uint4*)(Vh + ((long)(ktv) * 64 + lane) * (NKVH * HDIM) + (it_ * 4 + wave) * 8); }

#define SCATTER_V(dvv) {                                                   \
    _Pragma("unroll")                                                      \
    for (int it_ = 0; it_ < 4; ++it_) {                                    \
      const unsigned short* pv_ = (const unsigned short*)&dvv[it_];        \
      int seg_ = it_ * 4 + wave;                                           \
      _Pragma("unroll")                                                    \
      for (int e_ = 0; e_ < 8; ++e_) {                                     \
        int d_ = seg_ * 8 + e_;                                            \
        Vt[d_][((((lane >> 3) + d_) & 7) * 8) + (lane & 7)] = pv_[e_];     \
      } } }

  for (int pass = 0; pass < 2; ++pass) {
    const int qt = pass ? pr : (7 - pr);
    const int qbase = qt * 128;
    const int wq_lo = qbase + wave * 32;

    bf16x8 qa[2][4];
#pragma unroll
    for (int i = 0; i < 2; ++i) {
      const unsigned short* qrow =
          Qp + (long)(b * SEQ + wq_lo + i * 16 + m16) * (NHQ * HDIM) + h * HDIM;
#pragma unroll
      for (int kk = 0; kk < 4; ++kk)
        qa[i][kk] = *(const bf16x8*)(qrow + kk * 32 + quad * 8);
    }

    f32x4 o[2][8] = {};
    float mrow[2][4], lrow[2][4];
#pragma unroll
    for (int i = 0; i < 2; ++i)
#pragma unroll
      for (int r = 0; r < 4; ++r) { mrow[i][r] = -1e30f; lrow[i][r] = 0.f; }

    const int nkt = qt * 2 + 2;

    {  // prologue: K0 -> Ks[0], V0 -> Vt
      STAGE_K(0, Ks[0]);
      uint4 dv0[4];
      LOAD_V(0, dv0);
      asm volatile("s_waitcnt vmcnt(0)" ::: "memory");
      SCATTER_V(dv0);
    }
    __syncthreads();

    for (int kt = 0; kt < nkt; ++kt) {
      const int cb = kt & 1;
      const bool active = (kt * 64) <= (wq_lo + 31);
      const bool more = (kt + 1) < nkt;

      f32x4 s4[2][4] = {};
      if (active) {
        __builtin_amdgcn_s_setprio(1);
#pragma unroll
        for (int kk = 0; kk < 4; ++kk) {
          bf16x8 kbf[4];
#pragma unroll
          for (int j = 0; j < 4; ++j) {
            int row = j * 16 + m16;
            int cl = kk * 4 + quad;
            int ps = (cl & 8) | ((cl & 7) ^ (row & 7));
            kbf[j] = *(const bf16x8*)(&Ks[cb][row][ps * 8]);
          }
#pragma unroll
          for (int i = 0; i < 2; ++i)
#pragma unroll
            for (int j = 0; j < 4; ++j)
              s4[i][j] = __builtin_amdgcn_mfma_f32_16x16x32_bf16(qa[i][kk], kbf[j], s4[i][j], 0, 0, 0);
        }
        __builtin_amdgcn_s_setprio(0);
      }

      // T14: issue next tile's K staging + V reg loads early
      uint4 dv[4];
      if (more) {
        STAGE_K(kt + 1, Ks[cb ^ 1]);
        LOAD_V(kt + 1, dv);
      }
      asm volatile("" ::: "memory");

      if (active) {
        const bool full = (kt * 64 + 63) <= wq_lo;
#pragma unroll
        for (int i = 0; i < 2; ++i) {
#pragma unroll
          for (int r = 0; r < 4; ++r) {
            const int qrow = i * 16 + quad * 4 + r;
            const int qi = qbase + wave * 32 + qrow;
            float v[4];
#pragma unroll
            for (int j = 0; j < 4; ++j) {
              v[j] = s4[i][j][r] * ATT_SCALE_L2;
              if (!full && (kt * 64 + j * 16 + m16 > qi)) v[j] = -1e30f;
            }
            float mx = fmaxf(fmaxf(v[0], v[1]), fmaxf(v[2], v[3]));
            mx = fmaxf(mx, __shfl_xor(mx, 1));
            mx = fmaxf(mx, __shfl_xor(mx, 2));
            mx = fmaxf(mx, __shfl_xor(mx, 4));
            mx = fmaxf(mx, __shfl_xor(mx, 8));
            float mold = mrow[i][r];
            float mnew = fmaxf(mold, mx);
            float alpha = exp2f(mold - mnew);
            float rs = 0.f;
#pragma unroll
            for (int j = 0; j < 4; ++j) {
              float pj = exp2f(v[j] - mnew);
              rs += pj;
              int col = j * 16 + m16;
              Ps[wave][qrow][((((col >> 3) + qrow) & 7) * 8) + (col & 7)] = f2bf(pj);
            }
            rs += __shfl_xor(rs, 1); rs += __shfl_xor(rs, 2);
            rs += __shfl_xor(rs, 4); rs += __shfl_xor(rs, 8);
            lrow[i][r] = lrow[i][r] * alpha + rs;
            mrow[i][r] = mnew;
#pragma unroll
            for (int n = 0; n < 8; ++n) o[i][n][r] *= alpha;
          }
        }
        __builtin_amdgcn_s_setprio(1);
#pragma unroll
        for (int kk = 0; kk < 2; ++kk) {
          bf16x8 pa[2], vb[8];
#pragma unroll
          for (int i = 0; i < 2; ++i) {
            int row = i * 16 + m16;
            pa[i] = *(const bf16x8*)(&Ps[wave][row][(((kk * 4 + quad) + row) & 7) * 8]);
          }
#pragma unroll
          for (int n = 0; n < 8; ++n) {
            int row = n * 16 + m16;
            vb[n] = *(const bf16x8*)(&Vt[row][(((kk * 4 + quad) + row) & 7) * 8]);
          }
#pragma unroll
          for (int i = 0; i < 2; ++i)
#pragma unroll
            for (int n = 0; n < 8; ++n)
              o[i][n] = __builtin_amdgcn_mfma_f32_16x16x32_bf16(pa[i], vb[n], o[i][n], 0, 0, 0);
        }
        __builtin_amdgcn_s_setprio(0);
      }

      __syncthreads();                 // all PV reads of Vt done
      if (more) SCATTER_V(dv);
      __syncthreads();                 // scatter visible before next PV
    }

#pragma unroll
    for (int i = 0; i < 2; ++i) {
#pragma unroll
      for (int r = 0; r < 4; ++r) {
        float inv = 1.0f / lrow[i][r];
        unsigned short* orow =
            Op + (long)(b * SEQ + wq_lo + i * 16 + quad * 4 + r) * (NHQ * HDIM) + h * HDIM;
#pragma unroll
        for (int n = 0; n < 8; ++n)
          orow[n * 16 + m16] = f2bf(o[i][n][r] * inv);
      }
    }
  }
}

// ---------------- launch ----------------
extern "C" void kernel_launch(void* const* d_in, const int* in_sizes, int n_in,
                              void* d_out, int out_size, void* d_ws, size_t ws_size,
                              hipStream_t stream) {
  (void)in_sizes; (void)n_in; (void)out_size; (void)ws_size;
  const float* x  = (const float*)d_in[0];
  const int* pos  = (const int*)d_in[1];
  const float* wq = (const float*)d_in[3];
  const float* wk = (const float*)d_in[4];
  const float* wv = (const float*)d_in[5];
  const float* wo = (const float*)d_in[6];
  float* out = (float*)d_out;

  char* ws = (char*)d_ws;
  unsigned short* xb    = (unsigned short*)(ws);                   // 32MB bf16 x
  unsigned short* wqkv  = (unsigned short*)(ws + (32ll << 20));    // 48MB bf16 [wq;wk;wv]
  unsigned short* wob   = (unsigned short*)(ws + (80ll << 20));    // 32MB bf16 wo
  unsigned short* qr    = (unsigned short*)(ws + (112ll << 20));   // 32MB q roped bf16
  unsigned short* kr    = (unsigned short*)(ws + (144ll << 20));   // 8MB  k roped bf16
  unsigned short* vb_   = (unsigned short*)(ws + (152ll << 20));   // 8MB  v bf16
  unsigned short* ao    = (unsigned short*)(ws + (160ll << 20));   // 32MB attn out bf16

  cast_all_k<<<57344, 256, 0, stream>>>(x, wq, wk, wv, wo, xb, wqkv, wob);
  gemm8p<true><<<dim3(24, 16), 512, 0, stream>>>(xb, wqkv, nullptr, pos, qr, kr, vb_, 6144);
  attn_k<<<dim3(4, 32, 4), 256, 0, stream>>>(qr, kr, vb_, ao);
  gemm8p<false><<<dim3(16, 16), 512, 0, stream>>>(ao, wob, out, nullptr, nullptr, nullptr, nullptr, 4096);
}

// Round 8
// 657.110 us; speedup vs baseline: 1.1484x; 1.1329x over previous
//
#include <hip/hip_runtime.h>
#include <hip/hip_bf16.h>
#include <math.h>

#define T_TOK 4096
#define HID   4096
#define NHQ   32
#define NKVH  8
#define HDIM  128
#define SEQ   1024
#define NBATCH 4

typedef __attribute__((ext_vector_type(8))) short bf16x8;
typedef __attribute__((ext_vector_type(4))) float f32x4;

__device__ __forceinline__ unsigned short f2bf(float f) {
  union { float f; unsigned int u; } x; x.f = f;
  unsigned int r = x.u + 0x7FFFu + ((x.u >> 16) & 1u);
  return (unsigned short)(r >> 16);
}

// async global->LDS, 16B per lane. LDS dest must be wave-uniform base; HW adds lane*16.
#define GLOAD_LDS16(gp, lp)                                                        \
  __builtin_amdgcn_global_load_lds(                                                \
      (__attribute__((address_space(1))) void*)(unsigned long long)(const void*)(gp), \
      (__attribute__((address_space(3))) void*)(unsigned long long)(const void*)(lp), \
      16, 0, 0)

// ---------------- single fused cast fp32 -> bf16 for all 5 tensors -------------
__global__ __launch_bounds__(256) void cast_all_k(const float* __restrict__ x,
                                                  const float* __restrict__ wq,
                                                  const float* __restrict__ wk,
                                                  const float* __restrict__ wv,
                                                  const float* __restrict__ wo,
                                                  unsigned short* __restrict__ xb,
                                                  unsigned short* __restrict__ wqkv,
                                                  unsigned short* __restrict__ wob) {
  int i = blockIdx.x * 256 + threadIdx.x;  // float4 index, total 14680064
  const float* src; unsigned short* dst; int off;
  if (i < 4194304)       { src = x;  dst = xb;   off = i; }
  else if (i < 8388608)  { src = wq; dst = wqkv; off = i - 4194304; }
  else if (i < 9437184)  { src = wk; dst = wqkv + 16777216; off = i - 8388608; }
  else if (i < 10485760) { src = wv; dst = wqkv + 20971520; off = i - 9437184; }
  else                   { src = wo; dst = wob;  off = i - 10485760; }
  float4 f = ((const float4*)src)[off];
  ushort4 o;
  o.x = f2bf(f.x); o.y = f2bf(f.y); o.z = f2bf(f.z); o.w = f2bf(f.w);
  ((ushort4*)dst)[off] = o;
}

// ============== QKV GEMM (fused RoPE): C[4096,6144] = A @ B^T ==================
// R5-measured best (218.6 us): 256x128 tile, BK=64, 8 waves (4M x 2N), ring-3,
// 2-phase split, counted vmcnt(6), 0-conflict swizzle.
__global__ __launch_bounds__(512, 2) void gemm_qkv(const unsigned short* __restrict__ A,
                                                   const unsigned short* __restrict__ B,
                                                   const int* __restrict__ pos,
                                                   unsigned short* __restrict__ qr,
                                                   unsigned short* __restrict__ kr,
                                                   unsigned short* __restrict__ vbuf) {
  const int K = 4096, nt = 64;
  __shared__ unsigned short AS[3][16384];  // 96 KB: [256 rows][64 shorts] per slot
  __shared__ unsigned short BS[3][8192];   // 48 KB: [128 rows][64 shorts] per slot
  const int tid  = threadIdx.x;
  const int lane = tid & 63;
  const int wave = tid >> 6;
  const int m16  = lane & 15;
  const int quad = lane >> 4;
  const int wm   = wave >> 1;   // 0..3: rows wm*64..+63
  const int wn   = wave & 1;    // 0..1

  // XCD-aware swizzle (nwg = 768, %8==0)
  const int gx = 48;
  const int orig = blockIdx.y * gx + blockIdx.x;
  const int swz = (orig & 7) * 96 + (orig >> 3);
  const long rowBase = (long)(swz / gx) * 256;
  const long colBase = (long)(swz % gx) * 128;

  // loop-invariant LDS read offsets (shorts): row=base+m16, slot=(ks*4+quad)^(m16&7)
  int aoff[2], boff[2];
#pragma unroll
  for (int ks = 0; ks < 2; ++ks) {
    int sx = ((ks * 4 + quad) ^ (m16 & 7)) * 8;
    aoff[ks] = (wm * 64 + m16) * 64 + sx;
    boff[ks] = (wn * 32 + m16) * 64 + sx;
  }

  // staging source (inverse swizzle), R3-verified
  const long Kl = K;
  const int sck = ((tid & 7) ^ ((tid >> 3) & 7)) * 8;
  const unsigned short* gA = A + (rowBase + (tid >> 3)) * Kl + sck;
  const unsigned short* gB = B + (colBase + (tid >> 3)) * Kl + sck;
  const int dofs = wave * 512;

#define STG_B(slot_, ko_) { GLOAD_LDS16(gB + (ko_),            &BS[slot_][dofs]);         \
                            GLOAD_LDS16(gB + (ko_) + 64 * Kl,  &BS[slot_][4096 + dofs]); }
#define STG_A(slot_, ko_) { GLOAD_LDS16(gA + (ko_),            &AS[slot_][dofs]);         \
                            GLOAD_LDS16(gA + (ko_) + 64 * Kl,  &AS[slot_][4096 + dofs]);  \
                            GLOAD_LDS16(gA + (ko_) + 128 * Kl, &AS[slot_][8192 + dofs]);  \
                            GLOAD_LDS16(gA + (ko_) + 192 * Kl, &AS[slot_][12288 + dofs]); }

  f32x4 acc[4][4] = {};   // [mf][nf]

  // prologue: stage tiles 0 (slot 0) and 1 (slot 1); 6 loads each
  STG_A(0, 0); STG_B(0, 0);
  STG_A(1, 64); STG_B(1, 64);
  asm volatile("s_waitcnt vmcnt(6)" ::: "memory");   // tile0 landed, tile1 in flight
  __builtin_amdgcn_s_barrier();

  for (int g = 0; g < 22; ++g) {
#pragma unroll
    for (int u = 0; u < 3; ++u) {
      const int t = g * 3 + u;
      if (t < nt) {
        const bool doStage = (t + 2) < nt;
        const long kn = (long)(t + 2) * 64;
        bf16x8 af[4], bfr[4];

        // ---------- P1: ks=0 (8 ds_read) || stage A(t+2) ----------
#pragma unroll
        for (int mf = 0; mf < 4; ++mf)
          af[mf] = *(const bf16x8*)(&AS[u][aoff[0] + mf * 1024]);
#pragma unroll
        for (int nf = 0; nf < 4; ++nf)
          bfr[nf] = *(const bf16x8*)(&BS[u][boff[0] + (nf & 1) * 1024 + (nf >> 1) * 4096]);
        if (doStage) STG_A((u + 2) % 3, kn);
        __builtin_amdgcn_s_barrier();
        asm volatile("s_waitcnt lgkmcnt(0)" ::: "memory");
        __builtin_amdgcn_s_setprio(1);
#pragma unroll
        for (int mf = 0; mf < 4; ++mf)
#pragma unroll
          for (int nf = 0; nf < 4; ++nf)
            acc[mf][nf] = __builtin_amdgcn_mfma_f32_16x16x32_bf16(af[mf], bfr[nf], acc[mf][nf], 0, 0, 0);
        __builtin_amdgcn_s_setprio(0);
        __builtin_amdgcn_s_barrier();

        // ---------- P2: ks=1 (8 ds_read) || stage B(t+2), vmcnt(6) ----------
#pragma unroll
        for (int mf = 0; mf < 4; ++mf)
          af[mf] = *(const bf16x8*)(&AS[u][aoff[1] + mf * 1024]);
#pragma unroll
        for (int nf = 0; nf < 4; ++nf)
          bfr[nf] = *(const bf16x8*)(&BS[u][boff[1] + (nf & 1) * 1024 + (nf >> 1) * 4096]);
        if (doStage) STG_B((u + 2) % 3, kn);
        __builtin_amdgcn_s_barrier();
        asm volatile("s_waitcnt lgkmcnt(0)" ::: "memory");
        __builtin_amdgcn_s_setprio(1);
#pragma unroll
        for (int mf = 0; mf < 4; ++mf)
#pragma unroll
          for (int nf = 0; nf < 4; ++nf)
            acc[mf][nf] = __builtin_amdgcn_mfma_f32_16x16x32_bf16(af[mf], bfr[nf], acc[mf][nf], 0, 0, 0);
        __builtin_amdgcn_s_setprio(0);
        if (doStage)         asm volatile("s_waitcnt vmcnt(6)" ::: "memory");
        else if (t + 1 < nt) asm volatile("s_waitcnt vmcnt(0)" ::: "memory");
        __builtin_amdgcn_s_barrier();
      }
    }
  }

  // ---- fused epilogue: RoPE (q/k) or plain (v), bf16 scatter ----
  const int n0 = (int)colBase;   // 128-aligned head window
  unsigned short* dst;
  int rstride, colofs;
  bool dorope;
  if (n0 < 4096)       { dst = qr;   rstride = NHQ * HDIM;  colofs = n0;        dorope = true; }
  else if (n0 < 5120)  { dst = kr;   rstride = NKVH * HDIM; colofs = n0 - 4096; dorope = true; }
  else                 { dst = vbuf; rstride = NKVH * HDIM; colofs = n0 - 5120; dorope = false; }
  const float c0 = -13.287712379549449f / 64.0f;  // -log2(10000)/64
  float fA[2], fB[2];
#pragma unroll
  for (int e = 0; e < 2; ++e) {
    int d = wn * 32 + e * 16 + m16;
    fA[e] = exp2f(c0 * (float)(d >> 1));
    fB[e] = exp2f(c0 * (float)((d >> 1) + 32));
  }
#pragma unroll
  for (int mf = 0; mf < 4; ++mf) {
#pragma unroll
    for (int reg = 0; reg < 4; ++reg) {
      int grow = (int)rowBase + wm * 64 + mf * 16 + quad * 4 + reg;
      unsigned short* drow = dst + (long)grow * rstride + colofs;
      if (dorope) {
        int p = pos[grow];
        p = p < 0 ? 0 : (p > SEQ - 1 ? SEQ - 1 : p);
        float pf = (float)p;
#pragma unroll
        for (int e = 0; e < 2; ++e) {
          int d = wn * 32 + e * 16 + m16;
          float lo = acc[mf][e][reg], hi = acc[mf][e + 2][reg];
          float s1, cc1, s2, cc2;
          __sincosf(pf * fA[e], &s1, &cc1);
          __sincosf(pf * fB[e], &s2, &cc2);
          drow[d]      = f2bf(lo * cc1 - hi * s1);
          drow[d + 64] = f2bf(hi * cc2 + lo * s2);
        }
      } else {
#pragma unroll
        for (int e = 0; e < 2; ++e) {
          int d = wn * 32 + e * 16 + m16;
          drow[d]      = f2bf(acc[mf][e][reg]);
          drow[d + 64] = f2bf(acc[mf][e + 2][reg]);
        }
      }
    }
  }
}

// ============ Output-proj GEMM: 8-phase quadrant 256x256 (R7, tail-free grid) ==
__global__ __launch_bounds__(512, 1) void gemm_o8(const unsigned short* __restrict__ A,
                                                  const unsigned short* __restrict__ B,
                                                  float* __restrict__ C) {
  const int K = 4096, nt = 64, N = 4096;
  __shared__ unsigned short AS[2][2][128][64];  // 64 KB [dbuf][half][row][col]
  __shared__ unsigned short BS[2][2][128][64];  // 64 KB
  const int tid  = threadIdx.x;
  const int lane = tid & 63;
  const int wave = tid >> 6;
  const int m16  = lane & 15;
  const int quad = lane >> 4;
  const int wm2  = wave >> 2;   // 0..1
  const int wn2  = wave & 3;    // 0..3

  const int gx = 16;
  const int nwg = 256;
  const int orig = blockIdx.y * gx + blockIdx.x;
  const int swz = (orig & 7) * (nwg >> 3) + (orig >> 3);
  const long rowBase = (long)(swz / gx) * 256;
  const long colBase = (long)(swz % gx) * 256;

  int aof[2], bof[2];
#pragma unroll
  for (int ks = 0; ks < 2; ++ks) {
    int sx = ((ks * 4 + quad) ^ (m16 & 7)) * 8;
    aof[ks] = (wm2 * 64 + m16) * 64 + sx;   // + mf*1024
    bof[ks] = (wn2 * 16 + m16) * 64 + sx;   // + nf*4096
  }

  const long Kl = K;
  const int sck = ((tid & 7) ^ ((tid >> 3) & 7)) * 8;
  const unsigned short* gA = A + (rowBase + (tid >> 3)) * Kl + sck;
  const unsigned short* gB = B + (colBase + (tid >> 3)) * Kl + sck;
  const int dofs = wave * 512;

#define STGO(XS_, gX_, db_, hf_, ko_) {                                                      \
    GLOAD_LDS16(gX_ + (long)((hf_) * 128) * Kl + (ko_),      ((unsigned short*)&XS_[db_][hf_][0][0]) + dofs);  \
    GLOAD_LDS16(gX_ + (long)((hf_) * 128 + 64) * Kl + (ko_), ((unsigned short*)&XS_[db_][hf_][64][0]) + dofs); }

#define RD_A(d_, qa_) {                                                   \
    const unsigned short* Ah_ = &AS[d_][qa_][0][0];                       \
    _Pragma("unroll") for (int mf = 0; mf < 4; ++mf)                      \
      _Pragma("unroll") for (int ks = 0; ks < 2; ++ks)                    \
        af[mf][ks] = *(const bf16x8*)(Ah_ + aof[ks] + mf * 1024); }

#define RD_B(d_, qb_, dst_) {                                             \
    const unsigned short* Bh_ = &BS[d_][qb_][0][0];                       \
    _Pragma("unroll") for (int nf = 0; nf < 2; ++nf)                      \
      _Pragma("unroll") for (int ks = 0; ks < 2; ++ks)                    \
        dst_[nf][ks] = *(const bf16x8*)(Bh_ + bof[ks] + nf * 4096); }

#define MFMA16(qa_, qb_, b_) {                                            \
    _Pragma("unroll") for (int mf = 0; mf < 4; ++mf)                      \
      _Pragma("unroll") for (int nf = 0; nf < 2; ++nf)                    \
        _Pragma("unroll") for (int ks = 0; ks < 2; ++ks)                  \
          acc[qa_][qb_][mf][nf] = __builtin_amdgcn_mfma_f32_16x16x32_bf16(\
              af[mf][ks], b_[nf][ks], acc[qa_][qb_][mf][nf], 0, 0, 0); }

  f32x4 acc[2][2][4][2] = {};   // [qa][qb][mf][nf]
  bf16x8 af[4][2], b0[2][2], b1[2][2];

  STGO(AS, gA, 0, 0, 0);   STGO(BS, gB, 0, 1, 0);
  STGO(AS, gA, 0, 1, 0);   STGO(BS, gB, 0, 0, 0);
  STGO(AS, gA, 1, 0, 64);  STGO(BS, gB, 1, 1, 64);
  STGO(AS, gA, 1, 1, 64);
  asm volatile("s_waitcnt vmcnt(6)" ::: "memory");
  __builtin_amdgcn_s_barrier();

#define KSTEP(n_, d_) {                                                               \
    RD_A(d_, 0); RD_B(d_, 0, b0);                                                     \
    if ((n_) + 1 < nt) STGO(BS, gB, (d_) ^ 1, 0, ((n_) + 1) * 64);                    \
    asm volatile("s_waitcnt lgkmcnt(8)" ::: "memory");                                \
    __builtin_amdgcn_s_barrier();                                                     \
    asm volatile("s_waitcnt lgkmcnt(0)" ::: "memory");                                \
    __builtin_amdgcn_s_setprio(1); MFMA16(0, 0, b0); __builtin_amdgcn_s_setprio(0);   \
    __builtin_amdgcn_s_barrier();                                                     \
    RD_B(d_, 1, b1);                                                                  \
    if ((n_) + 2 < nt) STGO(AS, gA, d_, 0, ((n_) + 2) * 64);                          \
    __builtin_amdgcn_s_barrier();                                                     \
    asm volatile("s_waitcnt lgkmcnt(0)" ::: "memory");                                \
    __builtin_amdgcn_s_setprio(1); MFMA16(0, 1, b1); __builtin_amdgcn_s_setprio(0);   \
    __builtin_amdgcn_s_barrier();                                                     \
    RD_A(d_, 1);                                                                      \
    if ((n_) + 2 < nt) STGO(BS, gB, d_, 1, ((n_) + 2) * 64);                          \
    __builtin_amdgcn_s_barrier();                                                     \
    asm volatile("s_waitcnt lgkmcnt(0)" ::: "memory");                                \
    __builtin_amdgcn_s_setprio(1); MFMA16(1, 1, b1); __builtin_amdgcn_s_setprio(0);   \
    __builtin_amdgcn_s_barrier();                                                     \
    if ((n_) + 2 < nt) STGO(AS, gA, d_, 1, ((n_) + 2) * 64);                          \
    __builtin_amdgcn_s_barrier();                                                     \
    __builtin_amdgcn_s_setprio(1); MFMA16(1, 0, b0); __builtin_amdgcn_s_setprio(0);   \
    if ((n_) + 2 < nt) asm volatile("s_waitcnt vmcnt(6)" ::: "memory");               \
    else               asm volatile("s_waitcnt vmcnt(0)" ::: "memory");               \
    __builtin_amdgcn_s_barrier(); }

  for (int it = 0; it < 32; ++it) {
    KSTEP(2 * it, 0);
    KSTEP(2 * it + 1, 1);
  }

#pragma unroll
  for (int qa = 0; qa < 2; ++qa)
#pragma unroll
    for (int qb = 0; qb < 2; ++qb)
#pragma unroll
      for (int mf = 0; mf < 4; ++mf)
#pragma unroll
        for (int nf = 0; nf < 2; ++nf) {
          long c = colBase + qb * 128 + wn2 * 16 + nf * 64 + m16;
#pragma unroll
          for (int reg = 0; reg < 4; ++reg) {
            long row = rowBase + qa * 128 + wm2 * 64 + mf * 16 + quad * 4 + reg;
            C[row * N + c] = acc[qa][qb][mf][nf][reg];
          }
        }
}

// ---------------- Flash attention (causal, GQA), bf16 MFMA ----------------
// 8-wave blocks (512 thr, QBLK=256): grid (2,32,4)=256 blocks = 1 exact round;
// K/V staging shared by 8 waves (1.8x less staging). K dbuf + V dbuf -> ONE
// barrier per tile. T13 defer-max; deferred l-reduce (per-lane partials).
#define ATT_SCALE_L2 0.12754227022f  // (1/sqrt(128)) * log2(e)
#define RESCALE_THR 8.0f
__global__ __launch_bounds__(512) void attn8(const unsigned short* __restrict__ Qp,
                                             const unsigned short* __restrict__ Kp,
                                             const unsigned short* __restrict__ Vp,
                                             unsigned short* __restrict__ Op) {
  const int pr = blockIdx.x, h = blockIdx.y, b = blockIdx.z;
  const int kvh = h >> 2;
  const int tid = threadIdx.x, wave = tid >> 6, lane = tid & 63;
  const int m16 = lane & 15, quad = lane >> 4;

  __shared__ unsigned short Ks[2][64][128];   // 32 KB dbuf [key][d], xor swizzle
  __shared__ unsigned short Vt[2][128][64];   // 32 KB dbuf [d][key], rotation
  __shared__ unsigned short Ps[8][32][64];    // 32 KB per-wave P

  const unsigned short* Kh = Kp + (long)(b * SEQ) * (NKVH * HDIM) + kvh * HDIM;
  const unsigned short* Vh = Vp + (long)(b * SEQ) * (NKVH * HDIM) + kvh * HDIM;

  // 1024 16B units over 512 threads: 2 iters. Same (row,psg)->src mapping as
  // the verified 4-wave version; dest contiguous per wave.
#define STAGE_K8(ktv, bufp) {                                              \
    _Pragma("unroll")                                                      \
    for (int it_ = 0; it_ < 2; ++it_) {                                    \
      int c_ = it_ * 512 + tid;                                            \
      int row_ = c_ >> 4, psg_ = c_ & 15;                                  \
      int sg_ = (psg_ & 8) | ((psg_ & 7) ^ (row_ & 7));                    \
      GLOAD_LDS16(Kh + ((long)(ktv) * 64 + row_) * (NKVH * HDIM) + sg_ * 8,\
                  ((unsigned short*)(bufp)) + (it_ * 512 + wave * 64) * 8);\
    } }

#define LOAD_V8(ktv, dvv) {                                                \
    _Pragma("unroll")                                                      \
    for (int it_ = 0; it_ < 2; ++it_)                                      \
      dvv[it_] = *(const uint4*)(Vh + ((long)(ktv) * 64 + lane) * (NKVH * HDIM) + (it_ * 8 + wave) * 8); }

#define SCATTER_V8(bufp, dvv) {                                            \
    _Pragma("unroll")                                                      \
    for (int it_ = 0; it_ < 2; ++it_) {                                    \
      const unsigned short* pv_ = (const unsigned short*)&dvv[it_];        \
      int seg_ = it_ * 8 + wave;                                           \
      _Pragma("unroll")                                                    \
      for (int e_ = 0; e_ < 8; ++e_) {                                     \
        int d_ = seg_ * 8 + e_;                                            \
        (bufp)[d_][((((lane >> 3) + d_) & 7) * 8) + (lane & 7)] = pv_[e_]; \
      } } }

  for (int pass = 0; pass < 2; ++pass) {
    const int qt = pass ? pr : (3 - pr);       // pr in {0,1}; tiles of 256 q-rows
    const int qbase = qt * 256;
    const int wq_lo = qbase + wave * 32;

    bf16x8 qa[2][4];
#pragma unroll
    for (int i = 0; i < 2; ++i) {
      const unsigned short* qrow =
          Qp + (long)(b * SEQ + wq_lo + i * 16 + m16) * (NHQ * HDIM) + h * HDIM;
#pragma unroll
      for (int kk = 0; kk < 4; ++kk)
        qa[i][kk] = *(const bf16x8*)(qrow + kk * 32 + quad * 8);
    }

    f32x4 o[2][8] = {};
    float mrow[2][4], lrow[2][4];   // lrow = per-lane partial (reduced at end)
#pragma unroll
    for (int i = 0; i < 2; ++i)
#pragma unroll
      for (int r = 0; r < 4; ++r) { mrow[i][r] = -1e30f; lrow[i][r] = 0.f; }

    const int nkt = (qt + 1) * 4;   // k-tiles of 64 covering causal span

    {  // prologue: K0 -> Ks[0], V0 -> Vt[0]
      STAGE_K8(0, Ks[0]);
      uint4 dv0[2];
      LOAD_V8(0, dv0);
      asm volatile("s_waitcnt vmcnt(0)" ::: "memory");
      SCATTER_V8(Vt[0], dv0);
    }
    __syncthreads();

    for (int kt = 0; kt < nkt; ++kt) {
      const int cb = kt & 1;
      const bool active = (kt * 64) <= (wq_lo + 31);
      const bool more = (kt + 1) < nkt;

      f32x4 s4[2][4] = {};
      if (active) {
        __builtin_amdgcn_s_setprio(1);
#pragma unroll
        for (int kk = 0; kk < 4; ++kk) {
          bf16x8 kbf[4];
#pragma unroll
          for (int j = 0; j < 4; ++j) {
            int row = j * 16 + m16;
            int cl = kk * 4 + quad;
            int ps = (cl & 8) | ((cl & 7) ^ (row & 7));
            kbf[j] = *(const bf16x8*)(&Ks[cb][row][ps * 8]);
          }
#pragma unroll
          for (int i = 0; i < 2; ++i)
#pragma unroll
            for (int j = 0; j < 4; ++j)
              s4[i][j] = __builtin_amdgcn_mfma_f32_16x16x32_bf16(qa[i][kk], kbf[j], s4[i][j], 0, 0, 0);
        }
        __builtin_amdgcn_s_setprio(0);
      }

      // T14: issue next tile's K staging + V reg loads early
      uint4 dv[2];
      if (more) {
        STAGE_K8(kt + 1, Ks[cb ^ 1]);
        LOAD_V8(kt + 1, dv);
      }
      asm volatile("" ::: "memory");

      if (active) {
        const bool full = (kt * 64 + 63) <= wq_lo;
#pragma unroll
        for (int i = 0; i < 2; ++i) {
#pragma unroll
          for (int r = 0; r < 4; ++r) {
            const int qrow = i * 16 + quad * 4 + r;
            const int qi = qbase + wave * 32 + qrow;
            float v[4];
#pragma unroll
            for (int j = 0; j < 4; ++j) {
              v[j] = s4[i][j][r] * ATT_SCALE_L2;
              if (!full && (kt * 64 + j * 16 + m16 > qi)) v[j] = -1e30f;
            }
            float mx = fmaxf(fmaxf(v[0], v[1]), fmaxf(v[2], v[3]));
            mx = fmaxf(mx, __shfl_xor(mx, 1));
            mx = fmaxf(mx, __shfl_xor(mx, 2));
            mx = fmaxf(mx, __shfl_xor(mx, 4));
            mx = fmaxf(mx, __shfl_xor(mx, 8));
            float mold = mrow[i][r];
            // T13 defer-max: keep old max unless it grew by > THR.
            bool skip = (mx <= mold + RESCALE_THR);
            float mnew = skip ? mold : mx;
            float rs = 0.f;
#pragma unroll
            for (int j = 0; j < 4; ++j) {
              float pj = exp2f(v[j] - mnew);
              rs += pj;
              int col = j * 16 + m16;
              Ps[wave][qrow][((((col >> 3) + qrow) & 7) * 8) + (col & 7)] = f2bf(pj);
            }
            if (!skip) {
              float alpha = exp2f(mold - mnew);   // 0 when mold=-1e30 (kills garbage)
              lrow[i][r] *= alpha;
#pragma unroll
              for (int n = 0; n < 8; ++n) o[i][n][r] *= alpha;
              mrow[i][r] = mnew;
            }
            lrow[i][r] += rs;                     // per-lane partial (4 cols)
          }
        }
        __builtin_amdgcn_s_setprio(1);
#pragma unroll
        for (int kk = 0; kk < 2; ++kk) {
          bf16x8 pa[2], vb[8];
#pragma unroll
          for (int i = 0; i < 2; ++i) {
            int row = i * 16 + m16;
            pa[i] = *(const bf16x8*)(&Ps[wave][row][(((kk * 4 + quad) + row) & 7) * 8]);
          }
#pragma unroll
          for (int n = 0; n < 8; ++n) {
            int row = n * 16 + m16;
            vb[n] = *(const bf16x8*)(&Vt[cb][row][(((kk * 4 + quad) + row) & 7) * 8]);
          }
#pragma unroll
          for (int i = 0; i < 2; ++i)
#pragma unroll
            for (int n = 0; n < 8; ++n)
              o[i][n] = __builtin_amdgcn_mfma_f32_16x16x32_bf16(pa[i], vb[n], o[i][n], 0, 0, 0);
        }
        __builtin_amdgcn_s_setprio(0);
      }

      if (more) {
        asm volatile("s_waitcnt vmcnt(0)" ::: "memory");  // dv ready + K-stage retired
        SCATTER_V8(Vt[cb ^ 1], dv);
      }
      __syncthreads();   // single barrier/tile: separates all buffer crossings
    }

#pragma unroll
    for (int i = 0; i < 2; ++i) {
#pragma unroll
      for (int r = 0; r < 4; ++r) {
        float ls = lrow[i][r];
        ls += __shfl_xor(ls, 1); ls += __shfl_xor(ls, 2);
        ls += __shfl_xor(ls, 4); ls += __shfl_xor(ls, 8);
        float inv = 1.0f / ls;
        unsigned short* orow =
            Op + (long)(b * SEQ + wq_lo + i * 16 + quad * 4 + r) * (NHQ * HDIM) + h * HDIM;
#pragma unroll
        for (int n = 0; n < 8; ++n)
          orow[n * 16 + m16] = f2bf(o[i][n][r] * inv);
      }
    }
  }
}

// ---------------- launch ----------------
extern "C" void kernel_launch(void* const* d_in, const int* in_sizes, int n_in,
                              void* d_out, int out_size, void* d_ws, size_t ws_size,
                              hipStream_t stream) {
  (void)in_sizes; (void)n_in; (void)out_size; (void)ws_size;
  const float* x  = (const float*)d_in[0];
  const int* pos  = (const int*)d_in[1];
  const float* wq = (const float*)d_in[3];
  const float* wk = (const float*)d_in[4];
  const float* wv = (const float*)d_in[5];
  const float* wo = (const float*)d_in[6];
  float* out = (float*)d_out;

  char* ws = (char*)d_ws;
  unsigned short* xb    = (unsigned short*)(ws);                   // 32MB bf16 x
  unsigned short* wqkv  = (unsigned short*)(ws + (32ll << 20));    // 48MB bf16 [wq;wk;wv]
  unsigned short* wob   = (unsigned short*)(ws + (80ll << 20));    // 32MB bf16 wo
  unsigned short* qr    = (unsigned short*)(ws + (112ll << 20));   // 32MB q roped bf16
  unsigned short* kr    = (unsigned short*)(ws + (144ll << 20));   // 8MB  k roped bf16
  unsigned short* vb_   = (unsigned short*)(ws + (152ll << 20));   // 8MB  v bf16
  unsigned short* ao    = (unsigned short*)(ws + (160ll << 20));   // 32MB attn out bf16

  cast_all_k<<<57344, 256, 0, stream>>>(x, wq, wk, wv, wo, xb, wqkv, wob);
  gemm_qkv<<<dim3(48, 16), 512, 0, stream>>>(xb, wqkv, pos, qr, kr, vb_);
  attn8<<<dim3(2, 32, 4), 512, 0, stream>>>(qr, kr, vb_, ao);
  gemm_o8<<<dim3(16, 16), 512, 0, stream>>>(ao, wob, out);
}